// Round 1
// baseline (550.085 us; speedup 1.0000x reference)
//
#include <hip/hip_runtime.h>

#define VN 49152
#define DEG 20
#define NB 2
#define MROWS (NB * VN)   // 98304 rows, channel innermost

static constexpr float BN_EPS = 1e-5f;

// ---------------- GEMM helper: 64 outputs for one row ----------------
template<int K, int LDW>
__device__ __forceinline__ void gemm_rowacc(const float* __restrict__ xr,
                                            const float* __restrict__ W,
                                            int col0, float acc[64]) {
  #pragma unroll 1
  for (int k = 0; k < K; k += 4) {
    float4 xv = *(const float4*)(xr + k);
    const float* __restrict__ wr = W + (size_t)k * LDW + col0;
    float xs0 = xv.x, xs1 = xv.y, xs2 = xv.z, xs3 = xv.w;
    #pragma unroll
    for (int o = 0; o < 64; ++o) acc[o] = fmaf(xs0, wr[o], acc[o]);
    #pragma unroll
    for (int o = 0; o < 64; ++o) acc[o] = fmaf(xs1, wr[LDW + o], acc[o]);
    #pragma unroll
    for (int o = 0; o < 64; ++o) acc[o] = fmaf(xs2, wr[2 * LDW + o], acc[o]);
    #pragma unroll
    for (int o = 0; o < 64; ++o) acc[o] = fmaf(xs3, wr[3 * LDW + o], acc[o]);
  }
}

// t1 = x @ W1 + b1   (K=128, N=64)
__global__ __launch_bounds__(256) void gemm1_k128(const float* __restrict__ X,
    const float* __restrict__ W, const float* __restrict__ bias,
    float* __restrict__ Y) {
  int r = blockIdx.x * 256 + threadIdx.x;
  const float* __restrict__ xr = X + (size_t)r * 128;
  float acc[64];
  #pragma unroll
  for (int o = 0; o < 64; ++o) acc[o] = bias[o];
  gemm_rowacc<128, 64>(xr, W, 0, acc);
  float* __restrict__ yr = Y + (size_t)r * 64;
  #pragma unroll
  for (int o = 0; o < 64; o += 4)
    *(float4*)(yr + o) = make_float4(acc[o], acc[o+1], acc[o+2], acc[o+3]);
}

// t2 = x0 @ W2[0] + x1 @ W2[1] + x2 @ W2[2] + b2  (three K=64, N=64)
// NOTE: Y may alias X0 — each thread reads its whole row before storing.
__global__ __launch_bounds__(256) void gemm2_cheb(const float* __restrict__ X0,
    const float* __restrict__ X1, const float* __restrict__ X2,
    const float* __restrict__ W, const float* __restrict__ bias,
    float* __restrict__ Y) {
  int r = blockIdx.x * 256 + threadIdx.x;
  size_t off = (size_t)r * 64;
  float acc[64];
  #pragma unroll
  for (int o = 0; o < 64; ++o) acc[o] = bias[o];
  gemm_rowacc<64, 64>(X0 + off, W,            0, acc);
  gemm_rowacc<64, 64>(X1 + off, W + 64 * 64,  0, acc);
  gemm_rowacc<64, 64>(X2 + off, W + 2*64*64,  0, acc);
  float* __restrict__ yr = Y + off;
  #pragma unroll
  for (int o = 0; o < 64; o += 4)
    *(float4*)(yr + o) = make_float4(acc[o], acc[o+1], acc[o+2], acc[o+3]);
}

// t3 = h2 @ W3 + b3   (K=64, N=128 split in two 64-col chunks via blockIdx.y)
__global__ __launch_bounds__(256) void gemm3_k64_n128(const float* __restrict__ X,
    const float* __restrict__ W, const float* __restrict__ bias,
    float* __restrict__ Y) {
  int r = blockIdx.x * 256 + threadIdx.x;
  int col0 = blockIdx.y * 64;
  float acc[64];
  #pragma unroll
  for (int o = 0; o < 64; ++o) acc[o] = bias[col0 + o];
  gemm_rowacc<64, 128>(X + (size_t)r * 64, W, col0, acc);
  float* __restrict__ yr = Y + (size_t)r * 128 + col0;
  #pragma unroll
  for (int o = 0; o < 64; o += 4)
    *(float4*)(yr + o) = make_float4(acc[o], acc[o+1], acc[o+2], acc[o+3]);
}

// ---------------- spmm: y = L x  (structured COO: diag + 20 nbrs/node) -----
// one wave per (b,v) row, lane = channel (F=64)
__global__ __launch_bounds__(256) void spmm_k(const float* __restrict__ Xin,
    const int* __restrict__ cols, const float* __restrict__ vals,
    float* __restrict__ Y) {
  int w = __builtin_amdgcn_readfirstlane((int)(threadIdx.x >> 6));
  int r = blockIdx.x * 4 + w;                 // global row in [0, MROWS)
  int lane = threadIdx.x & 63;
  int b = (r >= VN) ? 1 : 0;
  int v = r - b * VN;
  const size_t base = (size_t)b * VN * 64;
  float acc = vals[v] * Xin[(size_t)r * 64 + lane];
  const int*   __restrict__ cp = cols + VN + v * DEG;
  const float* __restrict__ vp = vals + VN + v * DEG;
  #pragma unroll
  for (int j = 0; j < DEG; ++j) {
    int c = cp[j];
    float wv = vp[j];
    acc = fmaf(wv, Xin[base + (size_t)c * 64 + lane], acc);
  }
  Y[(size_t)r * 64 + lane] = acc;
}

// y = 2 * (L x1) - x0
__global__ __launch_bounds__(256) void spmm2_k(const float* __restrict__ X1,
    const float* __restrict__ X0, const int* __restrict__ cols,
    const float* __restrict__ vals, float* __restrict__ Y) {
  int w = __builtin_amdgcn_readfirstlane((int)(threadIdx.x >> 6));
  int r = blockIdx.x * 4 + w;
  int lane = threadIdx.x & 63;
  int b = (r >= VN) ? 1 : 0;
  int v = r - b * VN;
  const size_t base = (size_t)b * VN * 64;
  size_t idx = (size_t)r * 64 + lane;
  float acc = vals[v] * X1[idx];
  const int*   __restrict__ cp = cols + VN + v * DEG;
  const float* __restrict__ vp = vals + VN + v * DEG;
  #pragma unroll
  for (int j = 0; j < DEG; ++j) {
    int c = cp[j];
    float wv = vp[j];
    acc = fmaf(wv, X1[base + (size_t)c * 64 + lane], acc);
  }
  Y[idx] = 2.0f * acc - X0[idx];
}

// ---------------- BN stats: per-channel sum & sumsq over all rows ----------
template<int N>
__global__ __launch_bounds__(256) void bn_stats(const float* __restrict__ T,
    int M, float* __restrict__ stats) {
  constexpr int RPB = 256 / N;      // rows per block-iteration
  int tid = threadIdx.x;
  int c = tid & (N - 1);
  int r = blockIdx.x * RPB + tid / N;
  int stride = gridDim.x * RPB;
  float s = 0.f, s2 = 0.f;
  for (; r < M; r += stride) {
    float x = T[(size_t)r * N + c];
    s += x; s2 += x * x;
  }
  __shared__ float ls[256], ls2[256];
  ls[tid] = s; ls2[tid] = s2;
  __syncthreads();
  if (tid < N) {
    float a = ls[tid], a2 = ls2[tid];
    #pragma unroll
    for (int k = 1; k < RPB; ++k) { a += ls[tid + k * N]; a2 += ls2[tid + k * N]; }
    atomicAdd(&stats[c], a);
    atomicAdd(&stats[N + c], a2);
  }
}

// ---------------- BN apply + ReLU (in-place safe) --------------------------
template<int N>
__global__ __launch_bounds__(256) void bn_apply(const float* __restrict__ T,
    float* __restrict__ Y, const float* __restrict__ gamma,
    const float* __restrict__ beta, const float* __restrict__ stats, int M) {
  size_t i4 = ((size_t)blockIdx.x * 256 + threadIdx.x) * 4;
  if (i4 >= (size_t)M * N) return;
  int c0 = (int)(i4 & (N - 1));
  float4 t = *(const float4*)(T + i4);
  float tv[4] = {t.x, t.y, t.z, t.w};
  float ov[4];
  float invM = 1.0f / M;
  #pragma unroll
  for (int j = 0; j < 4; ++j) {
    int c = c0 + j;
    float mean = stats[c] * invM;
    float var  = stats[N + c] * invM - mean * mean;
    float sc = gamma[c] * rsqrtf(var + BN_EPS);
    float sh = beta[c] - mean * sc;
    float y = fmaf(tv[j], sc, sh);
    ov[j] = y > 0.f ? y : 0.f;
  }
  *(float4*)(Y + i4) = make_float4(ov[0], ov[1], ov[2], ov[3]);
}

extern "C" void kernel_launch(void* const* d_in, const int* in_sizes, int n_in,
                              void* d_out, int out_size, void* d_ws, size_t ws_size,
                              hipStream_t stream) {
  const float* x    = (const float*)d_in[0];
  const int*   cols = (const int*)  d_in[2];
  const float* vals = (const float*)d_in[3];
  const float* W1   = (const float*)d_in[4];
  const float* b1   = (const float*)d_in[5];
  const float* g1   = (const float*)d_in[6];
  const float* be1  = (const float*)d_in[7];
  const float* W2   = (const float*)d_in[8];
  const float* b2   = (const float*)d_in[9];
  const float* g2   = (const float*)d_in[10];
  const float* be2  = (const float*)d_in[11];
  const float* W3   = (const float*)d_in[12];
  const float* b3   = (const float*)d_in[13];
  const float* g3   = (const float*)d_in[14];
  const float* be3  = (const float*)d_in[15];
  float* out = (float*)d_out;

  float* A  = (float*)d_ws;                      // 25 MB: t1 / h1 / t2 / h2
  float* B1 = A  + (size_t)MROWS * 64;           // 25 MB: x1
  float* C2 = B1 + (size_t)MROWS * 64;           // 25 MB: x2
  float* st = C2 + (size_t)MROWS * 64;           // 512 floats of stats
  float* st1 = st, *st2 = st + 128, *st3 = st + 256;

  hipMemsetAsync(st, 0, 512 * sizeof(float), stream);

  dim3 blk(256);
  int gemm_blocks = MROWS / 256;                 // 384
  int spmm_blocks = MROWS / 4;                   // 24576
  int ap64_blocks = (MROWS * 64 / 4) / 256;      // 6144
  int ap128_blocks = (MROWS * 128 / 4) / 256;    // 12288

  // Layer 1: K=1 Chebyshev (pure GEMM) + BN + ReLU
  gemm1_k128<<<gemm_blocks, blk, 0, stream>>>(x, W1, b1, A);
  bn_stats<64><<<1024, blk, 0, stream>>>(A, MROWS, st1);
  bn_apply<64><<<ap64_blocks, blk, 0, stream>>>(A, A, g1, be1, st1, MROWS);

  // Layer 2: K=3 Chebyshev
  spmm_k <<<spmm_blocks, blk, 0, stream>>>(A, cols, vals, B1);       // x1 = L h1
  spmm2_k<<<spmm_blocks, blk, 0, stream>>>(B1, A, cols, vals, C2);   // x2 = 2 L x1 - h1
  gemm2_cheb<<<gemm_blocks, blk, 0, stream>>>(A, B1, C2, W2, b2, A); // in-place over h1
  bn_stats<64><<<1024, blk, 0, stream>>>(A, MROWS, st2);
  bn_apply<64><<<ap64_blocks, blk, 0, stream>>>(A, A, g2, be2, st2, MROWS);

  // Layer 3: K=1 Chebyshev + BN + ReLU, straight into d_out
  dim3 g3grid(gemm_blocks, 2);
  gemm3_k64_n128<<<g3grid, blk, 0, stream>>>(A, W3, b3, out);
  bn_stats<128><<<1024, blk, 0, stream>>>(out, MROWS, st3);
  bn_apply<128><<<ap128_blocks, blk, 0, stream>>>(out, out, g3, be3, st3, MROWS);
}

// Round 2
// 503.056 us; speedup vs baseline: 1.0935x; 1.0935x over previous
//
#include <hip/hip_runtime.h>

#define VN 49152
#define DEG 20
#define NB 2
#define MROWS (NB * VN)   // 98304 rows, channel innermost

static constexpr float BN_EPS = 1e-5f;

// ---------------- GEMM helper: 32 outputs for one row ----------------
// acc[32] stays register-resident (R1 post-mortem: acc[64] spilled to
// scratch, VGPR_Count=40 -> 83us vs 15us floor).
template<int K, int LDW>
__device__ __forceinline__ void gemm_rowacc32(const float* __restrict__ xr,
                                              const float* __restrict__ W,
                                              int col0, float acc[32]) {
  #pragma unroll 1
  for (int k = 0; k < K; k += 4) {
    float4 xv = *(const float4*)(xr + k);
    const float* __restrict__ wr = W + (size_t)k * LDW + col0;
    float xs0 = xv.x, xs1 = xv.y, xs2 = xv.z, xs3 = xv.w;
    #pragma unroll
    for (int o = 0; o < 32; ++o) acc[o] = fmaf(xs0, wr[o], acc[o]);
    #pragma unroll
    for (int o = 0; o < 32; ++o) acc[o] = fmaf(xs1, wr[LDW + o], acc[o]);
    #pragma unroll
    for (int o = 0; o < 32; ++o) acc[o] = fmaf(xs2, wr[2 * LDW + o], acc[o]);
    #pragma unroll
    for (int o = 0; o < 32; ++o) acc[o] = fmaf(xs3, wr[3 * LDW + o], acc[o]);
  }
}

template<int LDW>
__device__ __forceinline__ void store32(float* __restrict__ yr, float acc[32]) {
  #pragma unroll
  for (int o = 0; o < 32; o += 4)
    *(float4*)(yr + o) = make_float4(acc[o], acc[o+1], acc[o+2], acc[o+3]);
}

// t1 = x @ W1 + b1   (K=128, N=64; blockIdx.y = col half)
__global__ __launch_bounds__(256) void gemm1_k128(const float* __restrict__ X,
    const float* __restrict__ W, const float* __restrict__ bias,
    float* __restrict__ Y) {
  int r = blockIdx.x * 256 + threadIdx.x;
  int col0 = blockIdx.y * 32;
  float acc[32];
  #pragma unroll
  for (int o = 0; o < 32; ++o) acc[o] = bias[col0 + o];
  gemm_rowacc32<128, 64>(X + (size_t)r * 128, W, col0, acc);
  store32<64>(Y + (size_t)r * 64 + col0, acc);
}

// t2 = x0 @ W2[0] + x1 @ W2[1] + x2 @ W2[2] + b2  (three K=64, N=64)
// Output must NOT alias any input (column-split => cross-block races).
__global__ __launch_bounds__(256) void gemm2_cheb(const float* __restrict__ X0,
    const float* __restrict__ X1, const float* __restrict__ X2,
    const float* __restrict__ W, const float* __restrict__ bias,
    float* __restrict__ Y) {
  int r = blockIdx.x * 256 + threadIdx.x;
  int col0 = blockIdx.y * 32;
  size_t off = (size_t)r * 64;
  float acc[32];
  #pragma unroll
  for (int o = 0; o < 32; ++o) acc[o] = bias[col0 + o];
  gemm_rowacc32<64, 64>(X0 + off, W,            col0, acc);
  gemm_rowacc32<64, 64>(X1 + off, W + 64 * 64,  col0, acc);
  gemm_rowacc32<64, 64>(X2 + off, W + 2*64*64,  col0, acc);
  store32<64>(Y + off + col0, acc);
}

// t3 = h2 @ W3 + b3   (K=64, N=128; blockIdx.y in [0,4) -> 32-col chunk)
__global__ __launch_bounds__(256) void gemm3_k64_n128(const float* __restrict__ X,
    const float* __restrict__ W, const float* __restrict__ bias,
    float* __restrict__ Y) {
  int r = blockIdx.x * 256 + threadIdx.x;
  int col0 = blockIdx.y * 32;
  float acc[32];
  #pragma unroll
  for (int o = 0; o < 32; ++o) acc[o] = bias[col0 + o];
  gemm_rowacc32<64, 128>(X + (size_t)r * 64, W, col0, acc);
  store32<128>(Y + (size_t)r * 128 + col0, acc);
}

// ---------------- spmm: y = L x  (structured COO: diag + 20 nbrs/node) -----
// one wave per (b,v) row, lane = channel (F=64)
__global__ __launch_bounds__(256) void spmm_k(const float* __restrict__ Xin,
    const int* __restrict__ cols, const float* __restrict__ vals,
    float* __restrict__ Y) {
  int w = __builtin_amdgcn_readfirstlane((int)(threadIdx.x >> 6));
  int r = blockIdx.x * 4 + w;                 // global row in [0, MROWS)
  int lane = threadIdx.x & 63;
  int b = (r >= VN) ? 1 : 0;
  int v = r - b * VN;
  const size_t base = (size_t)b * VN * 64;
  float acc = vals[v] * Xin[(size_t)r * 64 + lane];
  const int*   __restrict__ cp = cols + VN + v * DEG;
  const float* __restrict__ vp = vals + VN + v * DEG;
  #pragma unroll
  for (int j = 0; j < DEG; ++j) {
    int c = cp[j];
    float wv = vp[j];
    acc = fmaf(wv, Xin[base + (size_t)c * 64 + lane], acc);
  }
  Y[(size_t)r * 64 + lane] = acc;
}

// y = 2 * (L x1) - x0
__global__ __launch_bounds__(256) void spmm2_k(const float* __restrict__ X1,
    const float* __restrict__ X0, const int* __restrict__ cols,
    const float* __restrict__ vals, float* __restrict__ Y) {
  int w = __builtin_amdgcn_readfirstlane((int)(threadIdx.x >> 6));
  int r = blockIdx.x * 4 + w;
  int lane = threadIdx.x & 63;
  int b = (r >= VN) ? 1 : 0;
  int v = r - b * VN;
  const size_t base = (size_t)b * VN * 64;
  size_t idx = (size_t)r * 64 + lane;
  float acc = vals[v] * X1[idx];
  const int*   __restrict__ cp = cols + VN + v * DEG;
  const float* __restrict__ vp = vals + VN + v * DEG;
  #pragma unroll
  for (int j = 0; j < DEG; ++j) {
    int c = cp[j];
    float wv = vp[j];
    acc = fmaf(wv, X1[base + (size_t)c * 64 + lane], acc);
  }
  Y[idx] = 2.0f * acc - X0[idx];
}

// ---------------- BN stats: per-channel sum & sumsq over all rows ----------
template<int N>
__global__ __launch_bounds__(256) void bn_stats(const float* __restrict__ T,
    int M, float* __restrict__ stats) {
  constexpr int RPB = 256 / N;      // rows per block-iteration
  int tid = threadIdx.x;
  int c = tid & (N - 1);
  int r = blockIdx.x * RPB + tid / N;
  int stride = gridDim.x * RPB;
  float s = 0.f, s2 = 0.f;
  for (; r < M; r += stride) {
    float x = T[(size_t)r * N + c];
    s += x; s2 += x * x;
  }
  __shared__ float ls[256], ls2[256];
  ls[tid] = s; ls2[tid] = s2;
  __syncthreads();
  if (tid < N) {
    float a = ls[tid], a2 = ls2[tid];
    #pragma unroll
    for (int k = 1; k < RPB; ++k) { a += ls[tid + k * N]; a2 += ls2[tid + k * N]; }
    atomicAdd(&stats[c], a);
    atomicAdd(&stats[N + c], a2);
  }
}

// ---------------- BN apply + ReLU (in-place safe, or out-of-place) ---------
template<int N>
__global__ __launch_bounds__(256) void bn_apply(const float* __restrict__ T,
    float* __restrict__ Y, const float* __restrict__ gamma,
    const float* __restrict__ beta, const float* __restrict__ stats, int M) {
  size_t i4 = ((size_t)blockIdx.x * 256 + threadIdx.x) * 4;
  if (i4 >= (size_t)M * N) return;
  int c0 = (int)(i4 & (N - 1));
  float4 t = *(const float4*)(T + i4);
  float tv[4] = {t.x, t.y, t.z, t.w};
  float ov[4];
  float invM = 1.0f / M;
  #pragma unroll
  for (int j = 0; j < 4; ++j) {
    int c = c0 + j;
    float mean = stats[c] * invM;
    float var  = stats[N + c] * invM - mean * mean;
    float sc = gamma[c] * rsqrtf(var + BN_EPS);
    float sh = beta[c] - mean * sc;
    float y = fmaf(tv[j], sc, sh);
    ov[j] = y > 0.f ? y : 0.f;
  }
  *(float4*)(Y + i4) = make_float4(ov[0], ov[1], ov[2], ov[3]);
}

extern "C" void kernel_launch(void* const* d_in, const int* in_sizes, int n_in,
                              void* d_out, int out_size, void* d_ws, size_t ws_size,
                              hipStream_t stream) {
  const float* x    = (const float*)d_in[0];
  const int*   cols = (const int*)  d_in[2];
  const float* vals = (const float*)d_in[3];
  const float* W1   = (const float*)d_in[4];
  const float* b1   = (const float*)d_in[5];
  const float* g1   = (const float*)d_in[6];
  const float* be1  = (const float*)d_in[7];
  const float* W2   = (const float*)d_in[8];
  const float* b2   = (const float*)d_in[9];
  const float* g2   = (const float*)d_in[10];
  const float* be2  = (const float*)d_in[11];
  const float* W3   = (const float*)d_in[12];
  const float* b3   = (const float*)d_in[13];
  const float* g3   = (const float*)d_in[14];
  const float* be3  = (const float*)d_in[15];
  float* out = (float*)d_out;

  float* A  = (float*)d_ws;                      // 25 MB: t1 / h1 / h2
  float* B1 = A  + (size_t)MROWS * 64;           // 25 MB: x1
  float* C2 = B1 + (size_t)MROWS * 64;           // 25 MB: x2
  float* st = C2 + (size_t)MROWS * 64;           // 512 floats of stats
  float* st1 = st, *st2 = st + 128, *st3 = st + 256;
  // t2 (layer-2 GEMM out) is staged in d_out (50 MB, unused until layer 3)
  float* T2 = out;

  hipMemsetAsync(st, 0, 512 * sizeof(float), stream);

  dim3 blk(256);
  int rowb = MROWS / 256;                        // 384
  dim3 g64(rowb, 2);                             // N=64 GEMMs, 32-col chunks
  dim3 g128(rowb, 4);                            // N=128 GEMM
  int spmm_blocks = MROWS / 4;                   // 24576
  int ap64_blocks = (MROWS * 64 / 4) / 256;      // 6144
  int ap128_blocks = (MROWS * 128 / 4) / 256;    // 12288

  // Layer 1: K=1 Chebyshev (pure GEMM) + BN + ReLU
  gemm1_k128<<<g64, blk, 0, stream>>>(x, W1, b1, A);
  bn_stats<64><<<1024, blk, 0, stream>>>(A, MROWS, st1);
  bn_apply<64><<<ap64_blocks, blk, 0, stream>>>(A, A, g1, be1, st1, MROWS);

  // Layer 2: K=3 Chebyshev
  spmm_k <<<spmm_blocks, blk, 0, stream>>>(A, cols, vals, B1);        // x1 = L h1
  spmm2_k<<<spmm_blocks, blk, 0, stream>>>(B1, A, cols, vals, C2);    // x2 = 2 L x1 - h1
  gemm2_cheb<<<g64, blk, 0, stream>>>(A, B1, C2, W2, b2, T2);         // t2 -> d_out (temp)
  bn_stats<64><<<1024, blk, 0, stream>>>(T2, MROWS, st2);
  bn_apply<64><<<ap64_blocks, blk, 0, stream>>>(T2, A, g2, be2, st2, MROWS); // h2 -> A

  // Layer 3: K=1 Chebyshev + BN + ReLU, straight into d_out
  gemm3_k64_n128<<<g128, blk, 0, stream>>>(A, W3, b3, out);
  bn_stats<128><<<1024, blk, 0, stream>>>(out, MROWS, st3);
  bn_apply<128><<<ap128_blocks, blk, 0, stream>>>(out, out, g3, be3, st3, MROWS);
}

// Round 3
// 342.328 us; speedup vs baseline: 1.6069x; 1.4695x over previous
//
#include <hip/hip_runtime.h>

#define VN 49152
#define DEG 20
#define NB 2
#define MROWS (NB * VN)   // 98304 rows, channel innermost

static constexpr float BN_EPS = 1e-5f;

typedef short bf16x8 __attribute__((ext_vector_type(8)));
typedef float floatx4 __attribute__((ext_vector_type(4)));

__device__ __forceinline__ unsigned short f2bf(float f) {
  unsigned int u = __builtin_bit_cast(unsigned int, f);
  u += 0x7FFFu + ((u >> 16) & 1u);            // RNE
  return (unsigned short)(u >> 16);
}
__device__ __forceinline__ float bf2f(unsigned short h) {
  unsigned int u = ((unsigned int)h) << 16;
  return __builtin_bit_cast(float, u);
}

// ======================= GEMM1: t1 = x @ W1 + b1 ===========================
// X fp32 [MROWS,128], W fp32 [128,64], Y bf16 [MROWS,64]. MFMA 16x16x32 bf16.
// Block: 256 thr (4 waves), tile 128 rows x 64 cols. K=128 staged whole.
#define LDA1 136   // 128 + 8 pad (bf16 units); 2-way bank alias only
__global__ __launch_bounds__(256) void gemm1(const float* __restrict__ X,
    const float* __restrict__ W, const float* __restrict__ bias,
    unsigned short* __restrict__ Y) {
  __shared__ unsigned short As[128 * LDA1];   // A tile, row-major [128][K=128]
  __shared__ unsigned short Bs[64 * LDA1];    // B^T tile [n=64][K=128]
  int t = threadIdx.x;
  int row0 = blockIdx.x * 128;
  // stage A (fp32 -> bf16): 16384 floats
  const float* Xt = X + (size_t)row0 * 128;
  #pragma unroll
  for (int c = 0; c < 16; ++c) {
    int f4i = c * 256 + t;
    int row = f4i >> 5, k = (f4i & 31) * 4;
    float4 v = *(const float4*)(Xt + row * 128 + k);
    unsigned int p0 = f2bf(v.x) | ((unsigned int)f2bf(v.y) << 16);
    unsigned int p1 = f2bf(v.z) | ((unsigned int)f2bf(v.w) << 16);
    *(uint2*)(&As[row * LDA1 + k]) = make_uint2(p0, p1);
  }
  // stage B^T (transpose + cvt): 8192 floats
  #pragma unroll
  for (int c = 0; c < 32; ++c) {
    int f = c * 256 + t;
    int k = f >> 6, n = f & 63;
    Bs[n * LDA1 + k] = f2bf(W[f]);
  }
  __syncthreads();
  int l = t & 63, wv = t >> 6;
  int lr = l & 15, q = l >> 4;
  int m0 = wv * 32;
  floatx4 acc[2][4];
  #pragma unroll
  for (int mi = 0; mi < 2; ++mi)
    #pragma unroll
    for (int ni = 0; ni < 4; ++ni) acc[mi][ni] = (floatx4)(0.f);
  #pragma unroll
  for (int ks = 0; ks < 128; ks += 32) {
    bf16x8 af[2], bf[4];
    #pragma unroll
    for (int mi = 0; mi < 2; ++mi)
      af[mi] = *(const bf16x8*)(&As[(m0 + mi * 16 + lr) * LDA1 + ks + q * 8]);
    #pragma unroll
    for (int ni = 0; ni < 4; ++ni)
      bf[ni] = *(const bf16x8*)(&Bs[(ni * 16 + lr) * LDA1 + ks + q * 8]);
    #pragma unroll
    for (int mi = 0; mi < 2; ++mi)
      #pragma unroll
      for (int ni = 0; ni < 4; ++ni)
        acc[mi][ni] = __builtin_amdgcn_mfma_f32_16x16x32_bf16(af[mi], bf[ni], acc[mi][ni], 0, 0, 0);
  }
  #pragma unroll
  for (int ni = 0; ni < 4; ++ni) {
    int col = ni * 16 + lr;
    float bv = bias[col];
    #pragma unroll
    for (int mi = 0; mi < 2; ++mi)
      #pragma unroll
      for (int r = 0; r < 4; ++r) {
        int row = row0 + m0 + mi * 16 + q * 4 + r;
        Y[(size_t)row * 64 + col] = f2bf(acc[mi][ni][r] + bv);
      }
  }
}

// ========= GEMM2: t2 = h1@W2[0] + x1@W2[1] + x2@W2[2] + b2 (bf16 in) =======
// Terms staged sequentially through one A/B buffer. Output row-local: may
// alias an input plane (each block only touches its own 128-row band).
#define LDA2 72    // 64 + 8 pad
__global__ __launch_bounds__(256) void gemm2(const unsigned short* __restrict__ X0,
    const unsigned short* __restrict__ X1, const unsigned short* __restrict__ X2,
    const float* __restrict__ W, const float* __restrict__ bias,
    unsigned short* __restrict__ Y) {
  __shared__ unsigned short As[128 * LDA2];
  __shared__ unsigned short Bs[64 * LDA2];
  int t = threadIdx.x;
  int row0 = blockIdx.x * 128;
  int l = t & 63, wv = t >> 6;
  int lr = l & 15, q = l >> 4;
  int m0 = wv * 32;
  floatx4 acc[2][4];
  #pragma unroll
  for (int mi = 0; mi < 2; ++mi)
    #pragma unroll
    for (int ni = 0; ni < 4; ++ni) acc[mi][ni] = (floatx4)(0.f);

  for (int term = 0; term < 3; ++term) {
    const unsigned short* Xp = (term == 0) ? X0 : (term == 1) ? X1 : X2;
    const float* Wt = W + term * 64 * 64;
    // stage A: 128x64 bf16 = 2048 x ushort4
    const unsigned short* Xt = Xp + (size_t)row0 * 64;
    #pragma unroll
    for (int c = 0; c < 8; ++c) {
      int i = c * 256 + t;
      int row = i >> 4, k = (i & 15) * 4;
      *(uint2*)(&As[row * LDA2 + k]) = *(const uint2*)(Xt + row * 64 + k);
    }
    // stage B^T: 4096 floats
    #pragma unroll
    for (int c = 0; c < 16; ++c) {
      int f = c * 256 + t;
      int k = f >> 6, n = f & 63;
      Bs[n * LDA2 + k] = f2bf(Wt[f]);
    }
    __syncthreads();
    #pragma unroll
    for (int ks = 0; ks < 64; ks += 32) {
      bf16x8 af[2], bf[4];
      #pragma unroll
      for (int mi = 0; mi < 2; ++mi)
        af[mi] = *(const bf16x8*)(&As[(m0 + mi * 16 + lr) * LDA2 + ks + q * 8]);
      #pragma unroll
      for (int ni = 0; ni < 4; ++ni)
        bf[ni] = *(const bf16x8*)(&Bs[(ni * 16 + lr) * LDA2 + ks + q * 8]);
      #pragma unroll
      for (int mi = 0; mi < 2; ++mi)
        #pragma unroll
        for (int ni = 0; ni < 4; ++ni)
          acc[mi][ni] = __builtin_amdgcn_mfma_f32_16x16x32_bf16(af[mi], bf[ni], acc[mi][ni], 0, 0, 0);
    }
    __syncthreads();   // before next term overwrites LDS
  }
  #pragma unroll
  for (int ni = 0; ni < 4; ++ni) {
    int col = ni * 16 + lr;
    float bv = bias[col];
    #pragma unroll
    for (int mi = 0; mi < 2; ++mi)
      #pragma unroll
      for (int r = 0; r < 4; ++r) {
        int row = row0 + m0 + mi * 16 + q * 4 + r;
        Y[(size_t)row * 64 + col] = f2bf(acc[mi][ni][r] + bv);
      }
  }
}

// ====== GEMM3: t3 = h2 @ W3 + b3  (K=64, N=128; blockIdx.y = col half) =====
__global__ __launch_bounds__(256) void gemm3(const unsigned short* __restrict__ X,
    const float* __restrict__ W, const float* __restrict__ bias,
    unsigned short* __restrict__ Y) {
  __shared__ unsigned short As[128 * LDA2];
  __shared__ unsigned short Bs[64 * LDA2];
  int t = threadIdx.x;
  int row0 = blockIdx.x * 128;
  int n0 = blockIdx.y * 64;
  const unsigned short* Xt = X + (size_t)row0 * 64;
  #pragma unroll
  for (int c = 0; c < 8; ++c) {
    int i = c * 256 + t;
    int row = i >> 4, k = (i & 15) * 4;
    *(uint2*)(&As[row * LDA2 + k]) = *(const uint2*)(Xt + row * 64 + k);
  }
  #pragma unroll
  for (int c = 0; c < 16; ++c) {
    int f = c * 256 + t;
    int k = f >> 6, n = f & 63;
    Bs[n * LDA2 + k] = f2bf(W[k * 128 + n0 + n]);
  }
  __syncthreads();
  int l = t & 63, wv = t >> 6;
  int lr = l & 15, q = l >> 4;
  int m0 = wv * 32;
  floatx4 acc[2][4];
  #pragma unroll
  for (int mi = 0; mi < 2; ++mi)
    #pragma unroll
    for (int ni = 0; ni < 4; ++ni) acc[mi][ni] = (floatx4)(0.f);
  #pragma unroll
  for (int ks = 0; ks < 64; ks += 32) {
    bf16x8 af[2], bf[4];
    #pragma unroll
    for (int mi = 0; mi < 2; ++mi)
      af[mi] = *(const bf16x8*)(&As[(m0 + mi * 16 + lr) * LDA2 + ks + q * 8]);
    #pragma unroll
    for (int ni = 0; ni < 4; ++ni)
      bf[ni] = *(const bf16x8*)(&Bs[(ni * 16 + lr) * LDA2 + ks + q * 8]);
    #pragma unroll
    for (int mi = 0; mi < 2; ++mi)
      #pragma unroll
      for (int ni = 0; ni < 4; ++ni)
        acc[mi][ni] = __builtin_amdgcn_mfma_f32_16x16x32_bf16(af[mi], bf[ni], acc[mi][ni], 0, 0, 0);
  }
  #pragma unroll
  for (int ni = 0; ni < 4; ++ni) {
    int col = n0 + ni * 16 + lr;
    float bv = bias[col];
    #pragma unroll
    for (int mi = 0; mi < 2; ++mi)
      #pragma unroll
      for (int r = 0; r < 4; ++r) {
        int row = row0 + m0 + mi * 16 + q * 4 + r;
        Y[(size_t)row * 128 + col] = f2bf(acc[mi][ni][r] + bv);
      }
  }
}

// ---------------- spmm (bf16 data): y = L x ----------------
__global__ __launch_bounds__(256) void spmm_k(const unsigned short* __restrict__ Xin,
    const int* __restrict__ cols, const float* __restrict__ vals,
    unsigned short* __restrict__ Y) {
  int w = __builtin_amdgcn_readfirstlane((int)(threadIdx.x >> 6));
  int r = blockIdx.x * 4 + w;
  int lane = threadIdx.x & 63;
  int b = (r >= VN) ? 1 : 0;
  int v = r - b * VN;
  const size_t base = (size_t)b * VN * 64;
  float acc = vals[v] * bf2f(Xin[(size_t)r * 64 + lane]);
  const int*   __restrict__ cp = cols + VN + v * DEG;
  const float* __restrict__ vp = vals + VN + v * DEG;
  #pragma unroll
  for (int j = 0; j < DEG; ++j) {
    int c = cp[j];
    float wv = vp[j];
    acc = fmaf(wv, bf2f(Xin[base + (size_t)c * 64 + lane]), acc);
  }
  Y[(size_t)r * 64 + lane] = f2bf(acc);
}

// y = 2 * (L x1) - x0
__global__ __launch_bounds__(256) void spmm2_k(const unsigned short* __restrict__ X1,
    const unsigned short* __restrict__ X0, const int* __restrict__ cols,
    const float* __restrict__ vals, unsigned short* __restrict__ Y) {
  int w = __builtin_amdgcn_readfirstlane((int)(threadIdx.x >> 6));
  int r = blockIdx.x * 4 + w;
  int lane = threadIdx.x & 63;
  int b = (r >= VN) ? 1 : 0;
  int v = r - b * VN;
  const size_t base = (size_t)b * VN * 64;
  size_t idx = (size_t)r * 64 + lane;
  float acc = vals[v] * bf2f(X1[idx]);
  const int*   __restrict__ cp = cols + VN + v * DEG;
  const float* __restrict__ vp = vals + VN + v * DEG;
  #pragma unroll
  for (int j = 0; j < DEG; ++j) {
    int c = cp[j];
    float wv = vp[j];
    acc = fmaf(wv, bf2f(X1[base + (size_t)c * 64 + lane]), acc);
  }
  Y[idx] = f2bf(2.0f * acc - bf2f(X0[idx]));
}

// ---------------- BN stats over bf16 plane ----------------
template<int N>
__global__ __launch_bounds__(256) void bn_stats_bf(const unsigned short* __restrict__ T,
    int M, float* __restrict__ stats) {
  constexpr int RPB = 256 / N;
  int tid = threadIdx.x;
  int c = tid & (N - 1);
  int r = blockIdx.x * RPB + tid / N;
  int stride = gridDim.x * RPB;
  float s = 0.f, s2 = 0.f;
  for (; r < M; r += stride) {
    float x = bf2f(T[(size_t)r * N + c]);
    s += x; s2 += x * x;
  }
  __shared__ float ls[256], ls2[256];
  ls[tid] = s; ls2[tid] = s2;
  __syncthreads();
  if (tid < N) {
    float a = ls[tid], a2 = ls2[tid];
    #pragma unroll
    for (int k = 1; k < RPB; ++k) { a += ls[tid + k * N]; a2 += ls2[tid + k * N]; }
    atomicAdd(&stats[c], a);
    atomicAdd(&stats[N + c], a2);
  }
}

// ---------------- BN apply + ReLU, bf16 -> bf16 (in-place safe) ------------
template<int N>
__global__ __launch_bounds__(256) void bn_apply_bf(const unsigned short* __restrict__ T,
    unsigned short* __restrict__ Y, const float* __restrict__ gamma,
    const float* __restrict__ beta, const float* __restrict__ stats, int M) {
  size_t i4 = ((size_t)blockIdx.x * 256 + threadIdx.x) * 4;
  if (i4 >= (size_t)M * N) return;
  int c0 = (int)(i4 & (N - 1));
  ushort4 tv = *(const ushort4*)(T + i4);
  unsigned short sv[4] = {tv.x, tv.y, tv.z, tv.w};
  unsigned short ov[4];
  float invM = 1.0f / M;
  #pragma unroll
  for (int j = 0; j < 4; ++j) {
    int c = c0 + j;
    float mean = stats[c] * invM;
    float var  = stats[N + c] * invM - mean * mean;
    float sc = gamma[c] * rsqrtf(var + BN_EPS);
    float sh = beta[c] - mean * sc;
    float y = fmaf(bf2f(sv[j]), sc, sh);
    ov[j] = f2bf(y > 0.f ? y : 0.f);
  }
  *(ushort4*)(Y + i4) = make_ushort4(ov[0], ov[1], ov[2], ov[3]);
}

// ---------------- BN apply + ReLU, bf16 -> fp32 (final layer) --------------
template<int N>
__global__ __launch_bounds__(256) void bn_apply_f32(const unsigned short* __restrict__ T,
    float* __restrict__ Y, const float* __restrict__ gamma,
    const float* __restrict__ beta, const float* __restrict__ stats, int M) {
  size_t i4 = ((size_t)blockIdx.x * 256 + threadIdx.x) * 4;
  if (i4 >= (size_t)M * N) return;
  int c0 = (int)(i4 & (N - 1));
  ushort4 tv = *(const ushort4*)(T + i4);
  unsigned short sv[4] = {tv.x, tv.y, tv.z, tv.w};
  float ov[4];
  float invM = 1.0f / M;
  #pragma unroll
  for (int j = 0; j < 4; ++j) {
    int c = c0 + j;
    float mean = stats[c] * invM;
    float var  = stats[N + c] * invM - mean * mean;
    float sc = gamma[c] * rsqrtf(var + BN_EPS);
    float sh = beta[c] - mean * sc;
    float y = fmaf(bf2f(sv[j]), sc, sh);
    ov[j] = y > 0.f ? y : 0.f;
  }
  *(float4*)(Y + i4) = make_float4(ov[0], ov[1], ov[2], ov[3]);
}

extern "C" void kernel_launch(void* const* d_in, const int* in_sizes, int n_in,
                              void* d_out, int out_size, void* d_ws, size_t ws_size,
                              hipStream_t stream) {
  const float* x    = (const float*)d_in[0];
  const int*   cols = (const int*)  d_in[2];
  const float* vals = (const float*)d_in[3];
  const float* W1   = (const float*)d_in[4];
  const float* b1   = (const float*)d_in[5];
  const float* g1   = (const float*)d_in[6];
  const float* be1  = (const float*)d_in[7];
  const float* W2   = (const float*)d_in[8];
  const float* b2   = (const float*)d_in[9];
  const float* g2   = (const float*)d_in[10];
  const float* be2  = (const float*)d_in[11];
  const float* W3   = (const float*)d_in[12];
  const float* b3   = (const float*)d_in[13];
  const float* g3   = (const float*)d_in[14];
  const float* be3  = (const float*)d_in[15];
  float* out = (float*)d_out;

  const size_t PL = (size_t)MROWS * 64;          // bf16 plane elements
  unsigned short* P0 = (unsigned short*)d_ws;    // t1 / h1
  unsigned short* P1 = P0 + PL;                  // x1 / t2 / h2
  unsigned short* P2 = P1 + PL;                  // x2, then t3 [MROWS,128]
  float* st = (float*)(P2 + 2 * PL);
  float* st1 = st, *st2 = st + 128, *st3 = st + 256;

  hipMemsetAsync(st, 0, 512 * sizeof(float), stream);

  dim3 blk(256);
  int rowb = MROWS / 128;                        // 768 row-tiles
  int spmm_blocks = MROWS / 4;                   // 24576
  int ap64_blocks = (int)(PL / 4 / 256);         // 6144
  int ap128_blocks = ap64_blocks * 2;            // 12288

  // Layer 1
  gemm1<<<rowb, blk, 0, stream>>>(x, W1, b1, P0);
  bn_stats_bf<64><<<1024, blk, 0, stream>>>(P0, MROWS, st1);
  bn_apply_bf<64><<<ap64_blocks, blk, 0, stream>>>(P0, P0, g1, be1, st1, MROWS);

  // Layer 2 (K=3 Chebyshev)
  spmm_k <<<spmm_blocks, blk, 0, stream>>>(P0, cols, vals, P1);          // x1
  spmm2_k<<<spmm_blocks, blk, 0, stream>>>(P1, P0, cols, vals, P2);      // x2
  gemm2<<<rowb, blk, 0, stream>>>(P0, P1, P2, W2, b2, P1);               // t2 (row-local overwrite of x1)
  bn_stats_bf<64><<<1024, blk, 0, stream>>>(P1, MROWS, st2);
  bn_apply_bf<64><<<ap64_blocks, blk, 0, stream>>>(P1, P1, g2, be2, st2, MROWS);

  // Layer 3
  dim3 g3grid(rowb, 2);
  gemm3<<<g3grid, blk, 0, stream>>>(P1, W3, b3, P2);                     // t3 bf16 [MROWS,128]
  bn_stats_bf<128><<<1024, blk, 0, stream>>>(P2, MROWS, st3);
  bn_apply_f32<128><<<ap128_blocks, blk, 0, stream>>>(P2, out, g3, be3, st3, MROWS);
}

// Round 4
// 320.783 us; speedup vs baseline: 1.7148x; 1.0672x over previous
//
#include <hip/hip_runtime.h>

#define VN 49152
#define DEG 20
#define NB 2
#define MROWS (NB * VN)   // 98304 rows

static constexpr float BN_EPS = 1e-5f;

typedef short bf16x8 __attribute__((ext_vector_type(8)));
typedef float floatx4 __attribute__((ext_vector_type(4)));

__device__ __forceinline__ unsigned short f2bf(float f) {
  unsigned int u = __builtin_bit_cast(unsigned int, f);
  u += 0x7FFFu + ((u >> 16) & 1u);            // RNE
  return (unsigned short)(u >> 16);
}
__device__ __forceinline__ float bf2f(unsigned short h) {
  unsigned int u = ((unsigned int)h) << 16;
  return __builtin_bit_cast(float, u);
}

// Feature planes (64-ch) are stored SWIZZLED as 4 sub-planes
// [batch][chalf][VN][32]: addr(b,v,ch) = ((b*2 + ch/32)*VN + v)*32 + ch%32.
// => a (batch,chalf) combo is a contiguous 3.15 MB region; 128B lines never
// straddle combos, so each combo's gather working set fits one XCD L2 (4MiB).

// ======================= GEMM1: t1 = x @ W1 + b1 ===========================
// X fp32 [MROWS,128] -> t1 bf16 SWZ. Also emits per-block BN partial stats.
#define LDA1 136
__global__ __launch_bounds__(256) void gemm1(const float* __restrict__ X,
    const float* __restrict__ W, const float* __restrict__ bias,
    unsigned short* __restrict__ Y, float* __restrict__ part) {
  __shared__ unsigned short As[128 * LDA1];
  __shared__ unsigned short Bs[64 * LDA1];
  __shared__ float sred[128];
  int t = threadIdx.x;
  int row0 = blockIdx.x * 128;
  if (t < 128) sred[t] = 0.f;
  const float* Xt = X + (size_t)row0 * 128;
  #pragma unroll
  for (int c = 0; c < 16; ++c) {
    int f4i = c * 256 + t;
    int row = f4i >> 5, k = (f4i & 31) * 4;
    float4 v = *(const float4*)(Xt + row * 128 + k);
    unsigned int p0 = f2bf(v.x) | ((unsigned int)f2bf(v.y) << 16);
    unsigned int p1 = f2bf(v.z) | ((unsigned int)f2bf(v.w) << 16);
    *(uint2*)(&As[row * LDA1 + k]) = make_uint2(p0, p1);
  }
  #pragma unroll
  for (int c = 0; c < 32; ++c) {
    int f = c * 256 + t;
    int k = f >> 6, n = f & 63;
    Bs[n * LDA1 + k] = f2bf(W[f]);
  }
  __syncthreads();
  int l = t & 63, wv = t >> 6;
  int lr = l & 15, q = l >> 4;
  int m0 = wv * 32;
  floatx4 acc[2][4];
  #pragma unroll
  for (int mi = 0; mi < 2; ++mi)
    #pragma unroll
    for (int ni = 0; ni < 4; ++ni) acc[mi][ni] = (floatx4)(0.f);
  #pragma unroll
  for (int ks = 0; ks < 128; ks += 32) {
    bf16x8 af[2], bfr[4];
    #pragma unroll
    for (int mi = 0; mi < 2; ++mi)
      af[mi] = *(const bf16x8*)(&As[(m0 + mi * 16 + lr) * LDA1 + ks + q * 8]);
    #pragma unroll
    for (int ni = 0; ni < 4; ++ni)
      bfr[ni] = *(const bf16x8*)(&Bs[(ni * 16 + lr) * LDA1 + ks + q * 8]);
    #pragma unroll
    for (int mi = 0; mi < 2; ++mi)
      #pragma unroll
      for (int ni = 0; ni < 4; ++ni)
        acc[mi][ni] = __builtin_amdgcn_mfma_f32_16x16x32_bf16(af[mi], bfr[ni], acc[mi][ni], 0, 0, 0);
  }
  int b = (row0 >= VN) ? 1 : 0;
  int vbase = row0 - b * VN + m0;
  #pragma unroll
  for (int ni = 0; ni < 4; ++ni) {
    int col = ni * 16 + lr;
    float bv = bias[col];
    size_t sub = (size_t)(b * 2 + (col >> 5)) * VN;
    float s = 0.f, s2 = 0.f;
    #pragma unroll
    for (int mi = 0; mi < 2; ++mi)
      #pragma unroll
      for (int r = 0; r < 4; ++r) {
        float y = acc[mi][ni][r] + bv;
        s += y; s2 += y * y;
        int v = vbase + mi * 16 + q * 4 + r;
        Y[(sub + v) * 32 + (col & 31)] = f2bf(y);
      }
    atomicAdd(&sred[col], s);
    atomicAdd(&sred[64 + col], s2);
  }
  __syncthreads();
  if (t < 128) part[(size_t)blockIdx.x * 128 + t] = sred[t];
}

// ===== GEMM2: t2 = h1@W2[0] + x1@W2[1] + x2@W2[2] + b2 ====================
// h1 = relu(bn1(t1)) applied during A-staging of term 0. Partial stats out.
#define LDA2 72
__global__ __launch_bounds__(256) void gemm2(const unsigned short* __restrict__ X0,
    const unsigned short* __restrict__ X1, const unsigned short* __restrict__ X2,
    const float* __restrict__ W, const float* __restrict__ bias,
    const float* __restrict__ scsh, unsigned short* __restrict__ Y,
    float* __restrict__ part) {
  __shared__ unsigned short As[128 * LDA2];
  __shared__ unsigned short Bs[64 * LDA2];
  __shared__ float sred[128];
  int t = threadIdx.x;
  int row0 = blockIdx.x * 128;
  int b = (row0 >= VN) ? 1 : 0;
  int b2 = b * 2;
  int vb0 = row0 - b * VN;
  if (t < 128) sred[t] = 0.f;
  int l = t & 63, wv = t >> 6;
  int lr = l & 15, q = l >> 4;
  int m0 = wv * 32;
  floatx4 acc[2][4];
  #pragma unroll
  for (int mi = 0; mi < 2; ++mi)
    #pragma unroll
    for (int ni = 0; ni < 4; ++ni) acc[mi][ni] = (floatx4)(0.f);

  for (int term = 0; term < 3; ++term) {
    const unsigned short* Xp = (term == 0) ? X0 : (term == 1) ? X1 : X2;
    const float* Wt = W + term * 64 * 64;
    #pragma unroll
    for (int c8 = 0; c8 < 8; ++c8) {
      int i = c8 * 256 + t;
      int row = i >> 4, k = (i & 15) * 4;
      const unsigned short* src = Xp + ((size_t)(b2 + (k >> 5)) * VN + vb0 + row) * 32 + (k & 31);
      uint2 rawv = *(const uint2*)src;
      if (term == 0) {
        unsigned short e[4] = {(unsigned short)(rawv.x & 0xFFFF), (unsigned short)(rawv.x >> 16),
                               (unsigned short)(rawv.y & 0xFFFF), (unsigned short)(rawv.y >> 16)};
        unsigned short o[4];
        #pragma unroll
        for (int jj = 0; jj < 4; ++jj) {
          float yv = fmaf(bf2f(e[jj]), scsh[k + jj], scsh[64 + k + jj]);
          o[jj] = f2bf(yv > 0.f ? yv : 0.f);
        }
        rawv = make_uint2(o[0] | ((unsigned int)o[1] << 16), o[2] | ((unsigned int)o[3] << 16));
      }
      *(uint2*)(&As[row * LDA2 + k]) = rawv;
    }
    #pragma unroll
    for (int c = 0; c < 16; ++c) {
      int f = c * 256 + t;
      int k = f >> 6, n = f & 63;
      Bs[n * LDA2 + k] = f2bf(Wt[f]);
    }
    __syncthreads();
    #pragma unroll
    for (int ks = 0; ks < 64; ks += 32) {
      bf16x8 af[2], bfr[4];
      #pragma unroll
      for (int mi = 0; mi < 2; ++mi)
        af[mi] = *(const bf16x8*)(&As[(m0 + mi * 16 + lr) * LDA2 + ks + q * 8]);
      #pragma unroll
      for (int ni = 0; ni < 4; ++ni)
        bfr[ni] = *(const bf16x8*)(&Bs[(ni * 16 + lr) * LDA2 + ks + q * 8]);
      #pragma unroll
      for (int mi = 0; mi < 2; ++mi)
        #pragma unroll
        for (int ni = 0; ni < 4; ++ni)
          acc[mi][ni] = __builtin_amdgcn_mfma_f32_16x16x32_bf16(af[mi], bfr[ni], acc[mi][ni], 0, 0, 0);
    }
    __syncthreads();
  }
  int vbase = vb0 + m0;
  #pragma unroll
  for (int ni = 0; ni < 4; ++ni) {
    int col = ni * 16 + lr;
    float bv = bias[col];
    size_t sub = (size_t)(b2 + (col >> 5)) * VN;
    float s = 0.f, s2 = 0.f;
    #pragma unroll
    for (int mi = 0; mi < 2; ++mi)
      #pragma unroll
      for (int r = 0; r < 4; ++r) {
        float y = acc[mi][ni][r] + bv;
        s += y; s2 += y * y;
        int v = vbase + mi * 16 + q * 4 + r;
        Y[(sub + v) * 32 + (col & 31)] = f2bf(y);
      }
    atomicAdd(&sred[col], s);
    atomicAdd(&sred[64 + col], s2);
  }
  __syncthreads();
  if (t < 128) part[(size_t)blockIdx.x * 128 + t] = sred[t];
}

// ====== GEMM3: t3 = h2 @ W3 + b3  (N=128; h2 = relu(bn2(t2)) in staging) ===
__global__ __launch_bounds__(256) void gemm3(const unsigned short* __restrict__ X,
    const float* __restrict__ W, const float* __restrict__ bias,
    const float* __restrict__ scsh, unsigned short* __restrict__ Y,
    float* __restrict__ part) {
  __shared__ unsigned short As[128 * LDA2];
  __shared__ unsigned short Bs[64 * LDA2];
  __shared__ float sred[128];
  int t = threadIdx.x;
  int row0 = blockIdx.x * 128;
  int n0 = blockIdx.y * 64;
  int b = (row0 >= VN) ? 1 : 0;
  int b2 = b * 2;
  int vb0 = row0 - b * VN;
  if (t < 128) sred[t] = 0.f;
  #pragma unroll
  for (int c8 = 0; c8 < 8; ++c8) {
    int i = c8 * 256 + t;
    int row = i >> 4, k = (i & 15) * 4;
    const unsigned short* src = X + ((size_t)(b2 + (k >> 5)) * VN + vb0 + row) * 32 + (k & 31);
    uint2 rawv = *(const uint2*)src;
    unsigned short e[4] = {(unsigned short)(rawv.x & 0xFFFF), (unsigned short)(rawv.x >> 16),
                           (unsigned short)(rawv.y & 0xFFFF), (unsigned short)(rawv.y >> 16)};
    unsigned short o[4];
    #pragma unroll
    for (int jj = 0; jj < 4; ++jj) {
      float yv = fmaf(bf2f(e[jj]), scsh[k + jj], scsh[64 + k + jj]);
      o[jj] = f2bf(yv > 0.f ? yv : 0.f);
    }
    *(uint2*)(&As[row * LDA2 + k]) =
        make_uint2(o[0] | ((unsigned int)o[1] << 16), o[2] | ((unsigned int)o[3] << 16));
  }
  #pragma unroll
  for (int c = 0; c < 16; ++c) {
    int f = c * 256 + t;
    int k = f >> 6, n = f & 63;
    Bs[n * LDA2 + k] = f2bf(W[k * 128 + n0 + n]);
  }
  __syncthreads();
  int l = t & 63, wv = t >> 6;
  int lr = l & 15, q = l >> 4;
  int m0 = wv * 32;
  floatx4 acc[2][4];
  #pragma unroll
  for (int mi = 0; mi < 2; ++mi)
    #pragma unroll
    for (int ni = 0; ni < 4; ++ni) acc[mi][ni] = (floatx4)(0.f);
  #pragma unroll
  for (int ks = 0; ks < 64; ks += 32) {
    bf16x8 af[2], bfr[4];
    #pragma unroll
    for (int mi = 0; mi < 2; ++mi)
      af[mi] = *(const bf16x8*)(&As[(m0 + mi * 16 + lr) * LDA2 + ks + q * 8]);
    #pragma unroll
    for (int ni = 0; ni < 4; ++ni)
      bfr[ni] = *(const bf16x8*)(&Bs[(ni * 16 + lr) * LDA2 + ks + q * 8]);
    #pragma unroll
    for (int mi = 0; mi < 2; ++mi)
      #pragma unroll
      for (int ni = 0; ni < 4; ++ni)
        acc[mi][ni] = __builtin_amdgcn_mfma_f32_16x16x32_bf16(af[mi], bfr[ni], acc[mi][ni], 0, 0, 0);
  }
  #pragma unroll
  for (int ni = 0; ni < 4; ++ni) {
    int lc = ni * 16 + lr;
    int col = n0 + lc;
    float bv = bias[col];
    float s = 0.f, s2 = 0.f;
    #pragma unroll
    for (int mi = 0; mi < 2; ++mi)
      #pragma unroll
      for (int r = 0; r < 4; ++r) {
        float y = acc[mi][ni][r] + bv;
        s += y; s2 += y * y;
        int row = row0 + m0 + mi * 16 + q * 4 + r;
        Y[(size_t)row * 128 + col] = f2bf(y);
      }
    atomicAdd(&sred[lc], s);
    atomicAdd(&sred[64 + lc], s2);
  }
  __syncthreads();
  if (t < 128)
    part[((size_t)blockIdx.y * 768 + blockIdx.x) * 128 + t] = sred[t];
}

// ---------------- reduce partials -> sc/sh -------------------------------
__global__ __launch_bounds__(128) void reduce_scsh64(const float* __restrict__ part,
    const float* __restrict__ gamma, const float* __restrict__ beta,
    float* __restrict__ scsh) {
  int t = threadIdx.x;              // t = s*64 + c
  const float* p = part + t;
  float a0 = 0.f, a1 = 0.f, a2 = 0.f, a3 = 0.f;
  for (int b = 0; b < 768; b += 4) {
    a0 += p[(size_t)(b + 0) * 128]; a1 += p[(size_t)(b + 1) * 128];
    a2 += p[(size_t)(b + 2) * 128]; a3 += p[(size_t)(b + 3) * 128];
  }
  __shared__ float sm[128];
  sm[t] = (a0 + a1) + (a2 + a3);
  __syncthreads();
  if (t < 64) {
    float mean = sm[t] * (1.f / MROWS);
    float var = sm[64 + t] * (1.f / MROWS) - mean * mean;
    float sc = gamma[t] * rsqrtf(var + BN_EPS);
    scsh[t] = sc;
    scsh[64 + t] = beta[t] - mean * sc;
  }
}

__global__ __launch_bounds__(256) void reduce_scsh128(const float* __restrict__ part,
    const float* __restrict__ gamma, const float* __restrict__ beta,
    float* __restrict__ scsh) {
  int t = threadIdx.x;              // t = s*128 + col
  int col = t & 127, s = t >> 7;
  int gy = col >> 6, lc = col & 63;
  const float* p = part + (size_t)gy * 768 * 128 + s * 64 + lc;
  float a0 = 0.f, a1 = 0.f, a2 = 0.f, a3 = 0.f;
  for (int gx = 0; gx < 768; gx += 4) {
    a0 += p[(size_t)(gx + 0) * 128]; a1 += p[(size_t)(gx + 1) * 128];
    a2 += p[(size_t)(gx + 2) * 128]; a3 += p[(size_t)(gx + 3) * 128];
  }
  __shared__ float sm[256];
  sm[s * 128 + col] = (a0 + a1) + (a2 + a3);
  __syncthreads();
  if (t < 128) {
    float mean = sm[t] * (1.f / MROWS);
    float var = sm[128 + t] * (1.f / MROWS) - mean * mean;
    float sc = gamma[t] * rsqrtf(var + BN_EPS);
    scsh[t] = sc;
    scsh[128 + t] = beta[t] - mean * sc;
  }
}

// ---------------- spmm1: x1 = L * relu(bn1(t1)) ---------------------------
// Block -> (batch, chalf) combo via blockIdx%8 (XCD pair), 8 rows/block,
// wave = 2 rows x 32 channels. Gather working set = 3.15 MB, L2-resident.
__global__ __launch_bounds__(256) void spmm1(const unsigned short* __restrict__ T1,
    const int* __restrict__ cols, const float* __restrict__ vals,
    const float* __restrict__ scsh, unsigned short* __restrict__ X1out) {
  int g = blockIdx.x;
  int combo = (g & 7) >> 1;
  int rowblock = ((g >> 3) << 1) | (g & 1);
  int t = threadIdx.x;
  int wv = t >> 6, lane = t & 63;
  int pair = lane >> 5, c = lane & 31;
  int v = rowblock * 8 + wv * 2 + pair;
  int ch = (combo & 1) * 32 + c;
  float sc = scsh[ch], sh = scsh[64 + ch];
  const unsigned short* plane = T1 + (size_t)combo * VN * 32;
  float w0 = vals[v];
  float x = bf2f(plane[(size_t)v * 32 + c]);
  float h = fmaf(x, sc, sh); h = h > 0.f ? h : 0.f;
  float acc = w0 * h;
  const int* cp = cols + VN + v * DEG;
  const float* vp = vals + VN + v * DEG;
  #pragma unroll
  for (int j = 0; j < DEG; ++j) {
    int cj = cp[j];
    float wj = vp[j];
    float xv = bf2f(plane[(size_t)cj * 32 + c]);
    float hv = fmaf(xv, sc, sh); hv = hv > 0.f ? hv : 0.f;
    acc = fmaf(wj, hv, acc);
  }
  __builtin_nontemporal_store(f2bf(acc), &X1out[(size_t)combo * VN * 32 + (size_t)v * 32 + c]);
}

// ------------- spmm2: x2 = 2*(L x1) - relu(bn1(t1)) -----------------------
__global__ __launch_bounds__(256) void spmm2(const unsigned short* __restrict__ X1,
    const unsigned short* __restrict__ T1, const int* __restrict__ cols,
    const float* __restrict__ vals, const float* __restrict__ scsh,
    unsigned short* __restrict__ X2out) {
  int g = blockIdx.x;
  int combo = (g & 7) >> 1;
  int rowblock = ((g >> 3) << 1) | (g & 1);
  int t = threadIdx.x;
  int wv = t >> 6, lane = t & 63;
  int pair = lane >> 5, c = lane & 31;
  int v = rowblock * 8 + wv * 2 + pair;
  int ch = (combo & 1) * 32 + c;
  float sc = scsh[ch], sh = scsh[64 + ch];
  const size_t pbase = (size_t)combo * VN * 32;
  const unsigned short* plane = X1 + pbase;
  float acc = vals[v] * bf2f(plane[(size_t)v * 32 + c]);
  const int* cp = cols + VN + v * DEG;
  const float* vp = vals + VN + v * DEG;
  #pragma unroll
  for (int j = 0; j < DEG; ++j) {
    int cj = cp[j];
    float wj = vp[j];
    acc = fmaf(wj, bf2f(plane[(size_t)cj * 32 + c]), acc);
  }
  unsigned short t1r = __builtin_nontemporal_load(&T1[pbase + (size_t)v * 32 + c]);
  float h0 = fmaf(bf2f(t1r), sc, sh); h0 = h0 > 0.f ? h0 : 0.f;
  __builtin_nontemporal_store(f2bf(2.0f * acc - h0), &X2out[pbase + (size_t)v * 32 + c]);
}

// ---------------- final BN apply + ReLU, bf16 -> fp32 ----------------------
__global__ __launch_bounds__(256) void bn_apply_final(const unsigned short* __restrict__ T,
    float* __restrict__ Y, const float* __restrict__ scsh) {
  size_t i4 = ((size_t)blockIdx.x * 256 + threadIdx.x) * 4;
  int c0 = (int)(i4 & 127);
  ushort4 tv = *(const ushort4*)(T + i4);
  unsigned short sv[4] = {tv.x, tv.y, tv.z, tv.w};
  float ov[4];
  #pragma unroll
  for (int j = 0; j < 4; ++j) {
    int c = c0 + j;
    float y = fmaf(bf2f(sv[j]), scsh[c], scsh[128 + c]);
    ov[j] = y > 0.f ? y : 0.f;
  }
  *(float4*)(Y + i4) = make_float4(ov[0], ov[1], ov[2], ov[3]);
}

extern "C" void kernel_launch(void* const* d_in, const int* in_sizes, int n_in,
                              void* d_out, int out_size, void* d_ws, size_t ws_size,
                              hipStream_t stream) {
  const float* x    = (const float*)d_in[0];
  const int*   cols = (const int*)  d_in[2];
  const float* vals = (const float*)d_in[3];
  const float* W1   = (const float*)d_in[4];
  const float* b1   = (const float*)d_in[5];
  const float* g1   = (const float*)d_in[6];
  const float* be1  = (const float*)d_in[7];
  const float* W2   = (const float*)d_in[8];
  const float* b2   = (const float*)d_in[9];
  const float* g2   = (const float*)d_in[10];
  const float* be2  = (const float*)d_in[11];
  const float* W3   = (const float*)d_in[12];
  const float* b3   = (const float*)d_in[13];
  const float* g3   = (const float*)d_in[14];
  const float* be3  = (const float*)d_in[15];
  float* out = (float*)d_out;

  const size_t PL = (size_t)MROWS * 64;          // 64-ch plane elements
  unsigned short* P0 = (unsigned short*)d_ws;    // t1 (SWZ)
  unsigned short* P1 = P0 + PL;                  // x1 / t2 (SWZ)
  unsigned short* P2 = P1 + PL;                  // x2 (SWZ), then t3 [MROWS,128]
  float* part  = (float*)(P2 + 2 * PL);          // 1536*128 floats
  float* scsh1 = part + 1536 * 128;              // 128
  float* scsh2 = scsh1 + 128;                    // 128
  float* scsh3 = scsh2 + 128;                    // 256

  dim3 blk(256);
  int rowb = MROWS / 128;                        // 768
  int spmm_blocks = MROWS / 4;                   // 24576 (8 rows per block, x2 combos interleave)
  int ap128_blocks = (int)(PL * 2 / 4 / 256);    // 12288

  // Layer 1
  gemm1<<<rowb, blk, 0, stream>>>(x, W1, b1, P0, part);
  reduce_scsh64<<<1, 128, 0, stream>>>(part, g1, be1, scsh1);

  // Layer 2 (K=3 Chebyshev); bn1-apply fused into consumers
  spmm1<<<spmm_blocks, blk, 0, stream>>>(P0, cols, vals, scsh1, P1);
  spmm2<<<spmm_blocks, blk, 0, stream>>>(P1, P0, cols, vals, scsh1, P2);
  gemm2<<<rowb, blk, 0, stream>>>(P0, P1, P2, W2, b2, scsh1, P1, part);
  reduce_scsh64<<<1, 128, 0, stream>>>(part, g2, be2, scsh2);

  // Layer 3; bn2-apply fused into gemm3 A-staging
  dim3 g3grid(rowb, 2);
  gemm3<<<g3grid, blk, 0, stream>>>(P1, W3, b3, scsh2, P2, part);
  reduce_scsh128<<<1, 256, 0, stream>>>(part, g3, be3, scsh3);
  bn_apply_final<<<ap128_blocks, blk, 0, stream>>>(P2, out, scsh3);
}

// Round 5
// 288.933 us; speedup vs baseline: 1.9038x; 1.1102x over previous
//
#include <hip/hip_runtime.h>

#define VN 49152
#define DEG 20
#define NB 2
#define MROWS (NB * VN)   // 98304 rows

static constexpr float BN_EPS = 1e-5f;

typedef short bf16x8 __attribute__((ext_vector_type(8)));
typedef float floatx4 __attribute__((ext_vector_type(4)));

__device__ __forceinline__ unsigned short f2bf(float f) {
  unsigned int u = __builtin_bit_cast(unsigned int, f);
  u += 0x7FFFu + ((u >> 16) & 1u);            // RNE
  return (unsigned short)(u >> 16);
}
__device__ __forceinline__ float bf2f(unsigned short h) {
  unsigned int u = ((unsigned int)h) << 16;
  return __builtin_bit_cast(float, u);
}
// packed-bf16 tricks: 1 VALU per element
__device__ __forceinline__ float bflo(unsigned int u) {
  return __builtin_bit_cast(float, u << 16);
}
__device__ __forceinline__ float bfhi(unsigned int u) {
  return __builtin_bit_cast(float, u & 0xFFFF0000u);
}
__device__ __forceinline__ unsigned int packbf(float a, float b) {
  return (unsigned int)f2bf(a) | ((unsigned int)f2bf(b) << 16);
}

// Feature planes (64-ch) are stored SWIZZLED as 4 sub-planes
// [batch][chalf][VN][32]: addr(b,v,ch) = ((b*2 + ch/32)*VN + v)*32 + ch%32.
// A (batch,chalf) combo = contiguous 3.15 MB -> fits one XCD L2.
// spmm blocks pin combo via blockIdx%8 so each combo lives on 2 XCDs.

// ======================= GEMM1: t1 = x @ W1 + b1 ===========================
#define LDA1 136
__global__ __launch_bounds__(256) void gemm1(const float* __restrict__ X,
    const float* __restrict__ W, const float* __restrict__ bias,
    unsigned short* __restrict__ Y, float* __restrict__ part) {
  __shared__ unsigned short As[128 * LDA1];
  __shared__ unsigned short Bs[64 * LDA1];
  __shared__ float sred[128];
  int t = threadIdx.x;
  int row0 = blockIdx.x * 128;
  if (t < 128) sred[t] = 0.f;
  const float* Xt = X + (size_t)row0 * 128;
  #pragma unroll
  for (int c = 0; c < 16; ++c) {
    int f4i = c * 256 + t;
    int row = f4i >> 5, k = (f4i & 31) * 4;
    float4 v = *(const float4*)(Xt + row * 128 + k);
    unsigned int p0 = packbf(v.x, v.y);
    unsigned int p1 = packbf(v.z, v.w);
    *(uint2*)(&As[row * LDA1 + k]) = make_uint2(p0, p1);
  }
  #pragma unroll
  for (int c = 0; c < 32; ++c) {
    int f = c * 256 + t;
    int k = f >> 6, n = f & 63;
    Bs[n * LDA1 + k] = f2bf(W[f]);
  }
  __syncthreads();
  int l = t & 63, wv = t >> 6;
  int lr = l & 15, q = l >> 4;
  int m0 = wv * 32;
  floatx4 acc[2][4];
  #pragma unroll
  for (int mi = 0; mi < 2; ++mi)
    #pragma unroll
    for (int ni = 0; ni < 4; ++ni) acc[mi][ni] = (floatx4)(0.f);
  #pragma unroll
  for (int ks = 0; ks < 128; ks += 32) {
    bf16x8 af[2], bfr[4];
    #pragma unroll
    for (int mi = 0; mi < 2; ++mi)
      af[mi] = *(const bf16x8*)(&As[(m0 + mi * 16 + lr) * LDA1 + ks + q * 8]);
    #pragma unroll
    for (int ni = 0; ni < 4; ++ni)
      bfr[ni] = *(const bf16x8*)(&Bs[(ni * 16 + lr) * LDA1 + ks + q * 8]);
    #pragma unroll
    for (int mi = 0; mi < 2; ++mi)
      #pragma unroll
      for (int ni = 0; ni < 4; ++ni)
        acc[mi][ni] = __builtin_amdgcn_mfma_f32_16x16x32_bf16(af[mi], bfr[ni], acc[mi][ni], 0, 0, 0);
  }
  int b = (row0 >= VN) ? 1 : 0;
  int vbase = row0 - b * VN + m0;
  #pragma unroll
  for (int ni = 0; ni < 4; ++ni) {
    int col = ni * 16 + lr;
    float bv = bias[col];
    size_t sub = (size_t)(b * 2 + (col >> 5)) * VN;
    float s = 0.f, s2 = 0.f;
    #pragma unroll
    for (int mi = 0; mi < 2; ++mi)
      #pragma unroll
      for (int r = 0; r < 4; ++r) {
        float y = acc[mi][ni][r] + bv;
        s += y; s2 += y * y;
        int v = vbase + mi * 16 + q * 4 + r;
        Y[(sub + v) * 32 + (col & 31)] = f2bf(y);
      }
    atomicAdd(&sred[col], s);
    atomicAdd(&sred[64 + col], s2);
  }
  __syncthreads();
  if (t < 128) part[(size_t)blockIdx.x * 128 + t] = sred[t];
}

// ===== GEMM2: t2 = h1@W2[0] + x1@W2[1] + x2@W2[2] + b2 (all raw bf16) =====
#define LDA2 72
__global__ __launch_bounds__(256) void gemm2(const unsigned short* __restrict__ X0,
    const unsigned short* __restrict__ X1, const unsigned short* __restrict__ X2,
    const float* __restrict__ W, const float* __restrict__ bias,
    unsigned short* __restrict__ Y, float* __restrict__ part) {
  __shared__ unsigned short As[128 * LDA2];
  __shared__ unsigned short Bs[64 * LDA2];
  __shared__ float sred[128];
  int t = threadIdx.x;
  int row0 = blockIdx.x * 128;
  int b = (row0 >= VN) ? 1 : 0;
  int b2 = b * 2;
  int vb0 = row0 - b * VN;
  if (t < 128) sred[t] = 0.f;
  int l = t & 63, wv = t >> 6;
  int lr = l & 15, q = l >> 4;
  int m0 = wv * 32;
  floatx4 acc[2][4];
  #pragma unroll
  for (int mi = 0; mi < 2; ++mi)
    #pragma unroll
    for (int ni = 0; ni < 4; ++ni) acc[mi][ni] = (floatx4)(0.f);

  for (int term = 0; term < 3; ++term) {
    const unsigned short* Xp = (term == 0) ? X0 : (term == 1) ? X1 : X2;
    const float* Wt = W + term * 64 * 64;
    #pragma unroll
    for (int c8 = 0; c8 < 8; ++c8) {
      int i = c8 * 256 + t;
      int row = i >> 4, k = (i & 15) * 4;
      const unsigned short* src = Xp + ((size_t)(b2 + (k >> 5)) * VN + vb0 + row) * 32 + (k & 31);
      *(uint2*)(&As[row * LDA2 + k]) = *(const uint2*)src;
    }
    #pragma unroll
    for (int c = 0; c < 16; ++c) {
      int f = c * 256 + t;
      int k = f >> 6, n = f & 63;
      Bs[n * LDA2 + k] = f2bf(Wt[f]);
    }
    __syncthreads();
    #pragma unroll
    for (int ks = 0; ks < 64; ks += 32) {
      bf16x8 af[2], bfr[4];
      #pragma unroll
      for (int mi = 0; mi < 2; ++mi)
        af[mi] = *(const bf16x8*)(&As[(m0 + mi * 16 + lr) * LDA2 + ks + q * 8]);
      #pragma unroll
      for (int ni = 0; ni < 4; ++ni)
        bfr[ni] = *(const bf16x8*)(&Bs[(ni * 16 + lr) * LDA2 + ks + q * 8]);
      #pragma unroll
      for (int mi = 0; mi < 2; ++mi)
        #pragma unroll
        for (int ni = 0; ni < 4; ++ni)
          acc[mi][ni] = __builtin_amdgcn_mfma_f32_16x16x32_bf16(af[mi], bfr[ni], acc[mi][ni], 0, 0, 0);
    }
    __syncthreads();
  }
  int vbase = vb0 + m0;
  #pragma unroll
  for (int ni = 0; ni < 4; ++ni) {
    int col = ni * 16 + lr;
    float bv = bias[col];
    size_t sub = (size_t)(b2 + (col >> 5)) * VN;
    float s = 0.f, s2 = 0.f;
    #pragma unroll
    for (int mi = 0; mi < 2; ++mi)
      #pragma unroll
      for (int r = 0; r < 4; ++r) {
        float y = acc[mi][ni][r] + bv;
        s += y; s2 += y * y;
        int v = vbase + mi * 16 + q * 4 + r;
        Y[(sub + v) * 32 + (col & 31)] = f2bf(y);
      }
    atomicAdd(&sred[col], s);
    atomicAdd(&sred[64 + col], s2);
  }
  __syncthreads();
  if (t < 128) part[(size_t)blockIdx.x * 128 + t] = sred[t];
}

// ====== GEMM3: t3 = h2 @ W3 + b3  (N=128; h2 = relu(bn2(t2)) in staging) ===
__global__ __launch_bounds__(256) void gemm3(const unsigned short* __restrict__ X,
    const float* __restrict__ W, const float* __restrict__ bias,
    const float* __restrict__ scsh, unsigned short* __restrict__ Y,
    float* __restrict__ part) {
  __shared__ unsigned short As[128 * LDA2];
  __shared__ unsigned short Bs[64 * LDA2];
  __shared__ float sred[128];
  int t = threadIdx.x;
  int row0 = blockIdx.x * 128;
  int n0 = blockIdx.y * 64;
  int b = (row0 >= VN) ? 1 : 0;
  int b2 = b * 2;
  int vb0 = row0 - b * VN;
  if (t < 128) sred[t] = 0.f;
  #pragma unroll
  for (int c8 = 0; c8 < 8; ++c8) {
    int i = c8 * 256 + t;
    int row = i >> 4, k = (i & 15) * 4;
    const unsigned short* src = X + ((size_t)(b2 + (k >> 5)) * VN + vb0 + row) * 32 + (k & 31);
    uint2 rawv = *(const uint2*)src;
    float y0 = fmaf(bflo(rawv.x), scsh[k + 0], scsh[64 + k + 0]);
    float y1 = fmaf(bfhi(rawv.x), scsh[k + 1], scsh[64 + k + 1]);
    float y2 = fmaf(bflo(rawv.y), scsh[k + 2], scsh[64 + k + 2]);
    float y3 = fmaf(bfhi(rawv.y), scsh[k + 3], scsh[64 + k + 3]);
    y0 = y0 > 0.f ? y0 : 0.f; y1 = y1 > 0.f ? y1 : 0.f;
    y2 = y2 > 0.f ? y2 : 0.f; y3 = y3 > 0.f ? y3 : 0.f;
    *(uint2*)(&As[row * LDA2 + k]) = make_uint2(packbf(y0, y1), packbf(y2, y3));
  }
  #pragma unroll
  for (int c = 0; c < 16; ++c) {
    int f = c * 256 + t;
    int k = f >> 6, n = f & 63;
    Bs[n * LDA2 + k] = f2bf(W[k * 128 + n0 + n]);
  }
  __syncthreads();
  int l = t & 63, wv = t >> 6;
  int lr = l & 15, q = l >> 4;
  int m0 = wv * 32;
  floatx4 acc[2][4];
  #pragma unroll
  for (int mi = 0; mi < 2; ++mi)
    #pragma unroll
    for (int ni = 0; ni < 4; ++ni) acc[mi][ni] = (floatx4)(0.f);
  #pragma unroll
  for (int ks = 0; ks < 64; ks += 32) {
    bf16x8 af[2], bfr[4];
    #pragma unroll
    for (int mi = 0; mi < 2; ++mi)
      af[mi] = *(const bf16x8*)(&As[(m0 + mi * 16 + lr) * LDA2 + ks + q * 8]);
    #pragma unroll
    for (int ni = 0; ni < 4; ++ni)
      bfr[ni] = *(const bf16x8*)(&Bs[(ni * 16 + lr) * LDA2 + ks + q * 8]);
    #pragma unroll
    for (int mi = 0; mi < 2; ++mi)
      #pragma unroll
      for (int ni = 0; ni < 4; ++ni)
        acc[mi][ni] = __builtin_amdgcn_mfma_f32_16x16x32_bf16(af[mi], bfr[ni], acc[mi][ni], 0, 0, 0);
  }
  #pragma unroll
  for (int ni = 0; ni < 4; ++ni) {
    int lc = ni * 16 + lr;
    int col = n0 + lc;
    float bv = bias[col];
    float s = 0.f, s2 = 0.f;
    #pragma unroll
    for (int mi = 0; mi < 2; ++mi)
      #pragma unroll
      for (int r = 0; r < 4; ++r) {
        float y = acc[mi][ni][r] + bv;
        s += y; s2 += y * y;
        int row = row0 + m0 + mi * 16 + q * 4 + r;
        Y[(size_t)row * 128 + col] = f2bf(y);
      }
    atomicAdd(&sred[lc], s);
    atomicAdd(&sred[64 + lc], s2);
  }
  __syncthreads();
  if (t < 128)
    part[((size_t)blockIdx.y * 768 + blockIdx.x) * 128 + t] = sred[t];
}

// ---------------- reduce partials -> sc/sh -------------------------------
__global__ __launch_bounds__(128) void reduce_scsh64(const float* __restrict__ part,
    const float* __restrict__ gamma, const float* __restrict__ beta,
    float* __restrict__ scsh) {
  int t = threadIdx.x;
  const float* p = part + t;
  float a0 = 0.f, a1 = 0.f, a2 = 0.f, a3 = 0.f;
  for (int b = 0; b < 768; b += 4) {
    a0 += p[(size_t)(b + 0) * 128]; a1 += p[(size_t)(b + 1) * 128];
    a2 += p[(size_t)(b + 2) * 128]; a3 += p[(size_t)(b + 3) * 128];
  }
  __shared__ float sm[128];
  sm[t] = (a0 + a1) + (a2 + a3);
  __syncthreads();
  if (t < 64) {
    float mean = sm[t] * (1.f / MROWS);
    float var = sm[64 + t] * (1.f / MROWS) - mean * mean;
    float sc = gamma[t] * rsqrtf(var + BN_EPS);
    scsh[t] = sc;
    scsh[64 + t] = beta[t] - mean * sc;
  }
}

__global__ __launch_bounds__(256) void reduce_scsh128(const float* __restrict__ part,
    const float* __restrict__ gamma, const float* __restrict__ beta,
    float* __restrict__ scsh) {
  int t = threadIdx.x;
  int col = t & 127, s = t >> 7;
  int gy = col >> 6, lc = col & 63;
  const float* p = part + (size_t)gy * 768 * 128 + s * 64 + lc;
  float a0 = 0.f, a1 = 0.f, a2 = 0.f, a3 = 0.f;
  for (int gx = 0; gx < 768; gx += 4) {
    a0 += p[(size_t)(gx + 0) * 128]; a1 += p[(size_t)(gx + 1) * 128];
    a2 += p[(size_t)(gx + 2) * 128]; a3 += p[(size_t)(gx + 3) * 128];
  }
  __shared__ float sm[256];
  sm[s * 128 + col] = (a0 + a1) + (a2 + a3);
  __syncthreads();
  if (t < 128) {
    float mean = sm[t] * (1.f / MROWS);
    float var = sm[128 + t] * (1.f / MROWS) - mean * mean;
    float sc = gamma[t] * rsqrtf(var + BN_EPS);
    scsh[t] = sc;
    scsh[128 + t] = beta[t] - mean * sc;
  }
}

// -------- bn_h1: h1 = relu(bn1(t1)), elementwise on swizzled plane --------
// Same block->combo mapping as spmm. 16B/lane.
__global__ __launch_bounds__(256) void bn_h1(const unsigned short* __restrict__ T1,
    const float* __restrict__ scsh, unsigned short* __restrict__ H1) {
  int g = blockIdx.x;
  int combo = (g & 7) >> 1;
  int rg = ((g >> 3) << 1) | (g & 1);
  int t = threadIdx.x;
  int wv = t >> 6, lane = t & 63;
  int v = rg * 64 + wv * 16 + (lane >> 2);
  int ch0 = (lane & 3) * 8;
  int cb = (combo & 1) * 32 + ch0;
  size_t off = (size_t)combo * VN * 32 + (size_t)v * 32 + ch0;
  uint4 d = *(const uint4*)(T1 + off);
  float y[8];
  y[0] = fmaf(bflo(d.x), scsh[cb + 0], scsh[64 + cb + 0]);
  y[1] = fmaf(bfhi(d.x), scsh[cb + 1], scsh[64 + cb + 1]);
  y[2] = fmaf(bflo(d.y), scsh[cb + 2], scsh[64 + cb + 2]);
  y[3] = fmaf(bfhi(d.y), scsh[cb + 3], scsh[64 + cb + 3]);
  y[4] = fmaf(bflo(d.z), scsh[cb + 4], scsh[64 + cb + 4]);
  y[5] = fmaf(bfhi(d.z), scsh[cb + 5], scsh[64 + cb + 5]);
  y[6] = fmaf(bflo(d.w), scsh[cb + 6], scsh[64 + cb + 6]);
  y[7] = fmaf(bfhi(d.w), scsh[cb + 7], scsh[64 + cb + 7]);
  #pragma unroll
  for (int j = 0; j < 8; ++j) y[j] = y[j] > 0.f ? y[j] : 0.f;
  uint4 o;
  o.x = packbf(y[0], y[1]); o.y = packbf(y[2], y[3]);
  o.z = packbf(y[4], y[5]); o.w = packbf(y[6], y[7]);
  *(uint4*)(H1 + off) = o;
}

// ---------------- spmm1: x1 = L h1  (raw gather, 16B/lane) -----------------
__global__ __launch_bounds__(256) void spmm1(const unsigned short* __restrict__ H1,
    const int* __restrict__ cols, const float* __restrict__ vals,
    unsigned short* __restrict__ X1out) {
  int g = blockIdx.x;
  int combo = (g & 7) >> 1;
  int rg = ((g >> 3) << 1) | (g & 1);
  int t = threadIdx.x;
  int wv = t >> 6, lane = t & 63;
  int v = rg * 64 + wv * 16 + (lane >> 2);
  int ch0 = (lane & 3) * 8;
  const unsigned short* __restrict__ plane = H1 + (size_t)combo * VN * 32;
  float a[8];
  {
    float w0 = vals[v];
    uint4 d = *(const uint4*)(plane + (size_t)v * 32 + ch0);
    a[0] = w0 * bflo(d.x); a[1] = w0 * bfhi(d.x);
    a[2] = w0 * bflo(d.y); a[3] = w0 * bfhi(d.y);
    a[4] = w0 * bflo(d.z); a[5] = w0 * bfhi(d.z);
    a[6] = w0 * bflo(d.w); a[7] = w0 * bfhi(d.w);
  }
  const int*   __restrict__ cp = cols + VN + v * DEG;
  const float* __restrict__ vp = vals + VN + v * DEG;
  #pragma unroll
  for (int j = 0; j < DEG; ++j) {
    int cj = cp[j];
    float wj = vp[j];
    uint4 d = *(const uint4*)(plane + (size_t)cj * 32 + ch0);
    a[0] = fmaf(bflo(d.x), wj, a[0]); a[1] = fmaf(bfhi(d.x), wj, a[1]);
    a[2] = fmaf(bflo(d.y), wj, a[2]); a[3] = fmaf(bfhi(d.y), wj, a[3]);
    a[4] = fmaf(bflo(d.z), wj, a[4]); a[5] = fmaf(bfhi(d.z), wj, a[5]);
    a[6] = fmaf(bflo(d.w), wj, a[6]); a[7] = fmaf(bfhi(d.w), wj, a[7]);
  }
  uint4 o;
  o.x = packbf(a[0], a[1]); o.y = packbf(a[2], a[3]);
  o.z = packbf(a[4], a[5]); o.w = packbf(a[6], a[7]);
  *(uint4*)(X1out + (size_t)combo * VN * 32 + (size_t)v * 32 + ch0) = o;
}

// ------------- spmm2: x2 = 2*(L x1) - h1 -----------------------------------
__global__ __launch_bounds__(256) void spmm2(const unsigned short* __restrict__ X1,
    const unsigned short* __restrict__ H1, const int* __restrict__ cols,
    const float* __restrict__ vals, unsigned short* __restrict__ X2out) {
  int g = blockIdx.x;
  int combo = (g & 7) >> 1;
  int rg = ((g >> 3) << 1) | (g & 1);
  int t = threadIdx.x;
  int wv = t >> 6, lane = t & 63;
  int v = rg * 64 + wv * 16 + (lane >> 2);
  int ch0 = (lane & 3) * 8;
  const size_t pbase = (size_t)combo * VN * 32;
  const size_t myoff = pbase + (size_t)v * 32 + ch0;
  const unsigned short* __restrict__ plane = X1 + pbase;
  float a[8];
  {
    float w0 = vals[v];
    uint4 d = *(const uint4*)(X1 + myoff);
    a[0] = w0 * bflo(d.x); a[1] = w0 * bfhi(d.x);
    a[2] = w0 * bflo(d.y); a[3] = w0 * bfhi(d.y);
    a[4] = w0 * bflo(d.z); a[5] = w0 * bfhi(d.z);
    a[6] = w0 * bflo(d.w); a[7] = w0 * bfhi(d.w);
  }
  const int*   __restrict__ cp = cols + VN + v * DEG;
  const float* __restrict__ vp = vals + VN + v * DEG;
  #pragma unroll
  for (int j = 0; j < DEG; ++j) {
    int cj = cp[j];
    float wj = vp[j];
    uint4 d = *(const uint4*)(plane + (size_t)cj * 32 + ch0);
    a[0] = fmaf(bflo(d.x), wj, a[0]); a[1] = fmaf(bfhi(d.x), wj, a[1]);
    a[2] = fmaf(bflo(d.y), wj, a[2]); a[3] = fmaf(bfhi(d.y), wj, a[3]);
    a[4] = fmaf(bflo(d.z), wj, a[4]); a[5] = fmaf(bfhi(d.z), wj, a[5]);
    a[6] = fmaf(bflo(d.w), wj, a[6]); a[7] = fmaf(bfhi(d.w), wj, a[7]);
  }
  uint4 h = *(const uint4*)(H1 + myoff);
  float hh[8] = {bflo(h.x), bfhi(h.x), bflo(h.y), bfhi(h.y),
                 bflo(h.z), bfhi(h.z), bflo(h.w), bfhi(h.w)};
  uint4 o;
  o.x = packbf(2.f * a[0] - hh[0], 2.f * a[1] - hh[1]);
  o.y = packbf(2.f * a[2] - hh[2], 2.f * a[3] - hh[3]);
  o.z = packbf(2.f * a[4] - hh[4], 2.f * a[5] - hh[5]);
  o.w = packbf(2.f * a[6] - hh[6], 2.f * a[7] - hh[7]);
  *(uint4*)(X2out + myoff) = o;
}

// ---------------- final BN apply + ReLU, bf16 -> fp32 ----------------------
__global__ __launch_bounds__(256) void bn_apply_final(const unsigned short* __restrict__ T,
    float* __restrict__ Y, const float* __restrict__ scsh) {
  size_t i4 = ((size_t)blockIdx.x * 256 + threadIdx.x) * 4;
  int c0 = (int)(i4 & 127);
  ushort4 tv = *(const ushort4*)(T + i4);
  unsigned short sv[4] = {tv.x, tv.y, tv.z, tv.w};
  float ov[4];
  #pragma unroll
  for (int j = 0; j < 4; ++j) {
    int c = c0 + j;
    float y = fmaf(bf2f(sv[j]), scsh[c], scsh[128 + c]);
    ov[j] = y > 0.f ? y : 0.f;
  }
  *(float4*)(Y + i4) = make_float4(ov[0], ov[1], ov[2], ov[3]);
}

extern "C" void kernel_launch(void* const* d_in, const int* in_sizes, int n_in,
                              void* d_out, int out_size, void* d_ws, size_t ws_size,
                              hipStream_t stream) {
  const float* x    = (const float*)d_in[0];
  const int*   cols = (const int*)  d_in[2];
  const float* vals = (const float*)d_in[3];
  const float* W1   = (const float*)d_in[4];
  const float* b1   = (const float*)d_in[5];
  const float* g1   = (const float*)d_in[6];
  const float* be1  = (const float*)d_in[7];
  const float* W2   = (const float*)d_in[8];
  const float* b2   = (const float*)d_in[9];
  const float* g2   = (const float*)d_in[10];
  const float* be2  = (const float*)d_in[11];
  const float* W3   = (const float*)d_in[12];
  const float* b3   = (const float*)d_in[13];
  const float* g3   = (const float*)d_in[14];
  const float* be3  = (const float*)d_in[15];
  float* out = (float*)d_out;

  const size_t PL = (size_t)MROWS * 64;          // plane elements
  unsigned short* P0 = (unsigned short*)d_ws;    // t1, then t2
  unsigned short* PH = P0 + PL;                  // h1
  unsigned short* P1 = PH + PL;                  // x1
  unsigned short* P2 = P1 + PL;                  // x2, then t3 [MROWS,128]
  float* part  = (float*)(P2 + 2 * PL);          // 1536*128 floats
  float* scsh1 = part + 1536 * 128;
  float* scsh2 = scsh1 + 128;
  float* scsh3 = scsh2 + 128;

  dim3 blk(256);
  int rowb = MROWS / 128;                        // 768
  int spmm_blocks = 3072;                        // 64 rows x 4 combos
  int ap128_blocks = (int)(PL * 2 / 4 / 256);    // 12288

  // Layer 1
  gemm1<<<rowb, blk, 0, stream>>>(x, W1, b1, P0, part);
  reduce_scsh64<<<1, 128, 0, stream>>>(part, g1, be1, scsh1);
  bn_h1<<<spmm_blocks, blk, 0, stream>>>(P0, scsh1, PH);

  // Layer 2 (K=3 Chebyshev), raw gathers on materialized h1
  spmm1<<<spmm_blocks, blk, 0, stream>>>(PH, cols, vals, P1);
  spmm2<<<spmm_blocks, blk, 0, stream>>>(P1, PH, cols, vals, P2);
  gemm2<<<rowb, blk, 0, stream>>>(PH, P1, P2, W2, b2, P0, part);   // t2 -> P0
  reduce_scsh64<<<1, 128, 0, stream>>>(part, g2, be2, scsh2);

  // Layer 3; bn2-apply fused into gemm3 A-staging
  dim3 g3grid(rowb, 2);
  gemm3<<<g3grid, blk, 0, stream>>>(P0, W3, b3, scsh2, P2, part);
  reduce_scsh128<<<1, 256, 0, stream>>>(part, g3, be3, scsh3);
  bn_apply_final<<<ap128_blocks, blk, 0, stream>>>(P2, out, scsh3);
}